// Round 1
// 131.430 us; speedup vs baseline: 1.0513x; 1.0513x over previous
//
#include <hip/hip_runtime.h>
#include <hip/hip_bf16.h>

// Problem constants (B=8,S=24,N=4096,K=9,C1=32,C2=16)
#define NB 8
#define NS 24
#define NN 4096
#define NC1 32
#define NC2 16
#define BN_COUNT 32768.0f

typedef float f32x4 __attribute__((ext_vector_type(4)));
typedef short bf16x8 __attribute__((ext_vector_type(8)));
union U8 { int4 i; bf16x8 b; };
union Q  { uint4 v; unsigned u[4]; };

#define PERM_LO 0x05040100u
#define PERM_HI 0x07060302u
// __builtin_amdgcn_perm(a, b, sel): bytes 0-3 = b, 4-7 = a.
// PERM_LO -> {lo16(b), lo16(a)} ; PERM_HI -> {hi16(b), hi16(a)}

__device__ __forceinline__ unsigned short bfbits(float x) {
    __hip_bfloat16 h = __float2bfloat16(x);
    return *(unsigned short*)&h;
}

// ---------------------------------------------------------------------------
// Kernel 1: input transpose to flat (k,n) layout + fused table builder
// (table code verbatim from the proven R9 body).
// flatT[bs*36864 + k*4096 + n] = input[bs*36864 + n*9 + k]
// ---------------------------------------------------------------------------
__global__ __launch_bounds__(256) void k_prep(const float* __restrict__ input,
                                              float* __restrict__ flatT,
                                              const int* __restrict__ neigh,
                                              int* __restrict__ G2M,
                                              int* __restrict__ G3M,
                                              const float* __restrict__ W2,
                                              const float* __restrict__ W3,
                                              __hip_bfloat16* __restrict__ W2B,
                                              __hip_bfloat16* __restrict__ W3B) {
    __shared__ __align__(16) float tile[9216];
    int blk = blockIdx.x;                 // 1100 = 768 transpose + 332 tables
    if (blk >= 768) {
        int j = (blk - 768) * 256 + threadIdx.x;     // < 84992
        if (j < 36864) {                             // G2M
            int j8 = j & 7;
            int tkbl = j >> 3;
            int l = tkbl & 63;
            int tkb = tkbl >> 6;                     // < 72
            int t = tkb / 9, kb = tkb - t * 9;
            int r = t * 16 + (l & 15);
            int k = kb * 32 + ((l >> 4) << 3) + j8;
            int rem = r * 288 + k;
            G2M[j] = neigh[(rem & 4095) * 9 + (rem >> 12)];
        } else if (j < 77824) {                      // G3M (40960)
            int t2 = j - 36864;
            int j8 = t2 & 7;
            int tkbl = t2 >> 3;
            int l = tkbl & 63;
            int tkb = tkbl >> 6;                     // < 80
            int t = tkb / 5, kb = tkb - t * 5;
            int r = t * 16 + (l & 15);
            int k = kb * 32 + ((l >> 4) << 3) + j8;
            int rem = r * 144 + k;
            G3M[t2] = (k < 144) ? neigh[(rem & 4095) * 9 + (rem >> 12)] : 0;
        } else if (j < 82432) {                      // W2B (4608)
            int jj = j - 77824;
            int kb = jj >> 9;
            int rest = jj & 511;
            int l = rest >> 3, j8 = rest & 7;
            int o = l & 15;
            int k = kb * 32 + ((l >> 4) << 3) + j8;
            W2B[jj] = __float2bfloat16(W2[o * 288 + k]);
        } else {                                     // W3B (2560)
            int jj = j - 82432;
            int kb = jj >> 9;
            int rest = jj & 511;
            int l = rest >> 3, j8 = rest & 7;
            int o = l & 15;
            int k = kb * 32 + ((l >> 4) << 3) + j8;
            W3B[jj] = __float2bfloat16((o == 0 && k < 144) ? W3[k] : 0.f);
        }
        return;
    }

    // transpose: block = (bs, quarter of n), tile = 1024 n-rows x 9 k
    int bs = blk >> 2, tt = blk & 3;
    int n0 = tt << 10;
    const float4* src = (const float4*)(input + (size_t)bs * 36864 + (size_t)n0 * 9);
    float4* tp = (float4*)tile;
    for (int j = threadIdx.x; j < 2304; j += 256) tp[j] = src[j];
    __syncthreads();
    float* dst = flatT + (size_t)bs * 36864 + n0;
    for (int j = threadIdx.x; j < 2304; j += 256) {
        int k = j >> 8, u = j & 255;                 // k 0..8, u 0..255
        float4 w;
        w.x = tile[(u * 4 + 0) * 9 + k];
        w.y = tile[(u * 4 + 1) * 9 + k];
        w.z = tile[(u * 4 + 2) * 9 + k];
        w.w = tile[(u * 4 + 3) * 9 + k];
        *(float4*)(dst + k * 4096 + u * 4) = w;
    }
}

// ---------------------------------------------------------------------------
// Kernel 2: FUSED layer1 + layer2. Per (bs, pl) block: compute the 8-channel
// h plane directly into LDS from flatT (bitwise-identical FMA order to the
// proven k_l1tab), then the proven R10 gather/perm/MFMA body unchanged.
// Block mapping pl-major so the 4 blocks per bs share one XCD's L2.
// ---------------------------------------------------------------------------
__global__ __launch_bounds__(512, 4) void k_l12(const float* __restrict__ flatT,
                                                const float* __restrict__ W1,
                                                const float* __restrict__ b1,
                                                const int4* __restrict__ G2M4,
                                                const int4* __restrict__ W2B4,
                                                const float* __restrict__ b2,
                                                __hip_bfloat16* __restrict__ y2p,
                                                float* __restrict__ psum,
                                                float* __restrict__ psq) {
    __shared__ __align__(16) uint4 hl[4096];       // 64 KB
    __shared__ float wred[2][8][16];
    int blk = blockIdx.x;                 // 768 = 4 pl * 192 bs, pl-major
    int pl = blk / 192;
    int bs = blk - pl * 192;

    int tid = threadIdx.x;
    int l = tid & 63, w = tid >> 6;       // w = r-tile 0..7
    int o = l & 15, q = l >> 4;

    // issue kb=0 index + B-frag loads first: latency overlaps the h compute
    const int4* gp = G2M4 + (size_t)(w * 9) * 128 + l * 2;
    int4 ia = gp[0];
    int4 ib = gp[1];
    U8 bf; bf.i = W2B4[l];

    // ---- fused layer 1: build this block's h plane in LDS ----
    // taps for point p are the contiguous floats flatT[p*9 .. p*9+8]
    const float* T = flatT + (size_t)bs * 36864;
    const float* W1s = W1 + pl * 72;      // 8 rows x 9, wave-uniform -> SGPR
    float b1v[8];
#pragma unroll
    for (int c = 0; c < 8; c++) b1v[c] = b1[pl * 8 + c];

#pragma unroll 2
    for (int j = 0; j < 8; j++) {
        int p = tid + 512 * j;
        const float* tp = T + p * 9;
        float v[9];
#pragma unroll
        for (int m = 0; m < 9; m++) v[m] = tp[m];
        uint4 d;
        unsigned* dp = (unsigned*)&d;
#pragma unroll
        for (int pr = 0; pr < 4; pr++) {
            float a0 = b1v[2 * pr], a1 = b1v[2 * pr + 1];
#pragma unroll
            for (int m = 0; m < 9; m++) a0 = fmaf(v[m], W1s[(2 * pr) * 9 + m], a0);
#pragma unroll
            for (int m = 0; m < 9; m++) a1 = fmaf(v[m], W1s[(2 * pr + 1) * 9 + m], a1);
            dp[pr] = (unsigned)bfbits(fmaxf(a0, 0.f)) |
                     ((unsigned)bfbits(fmaxf(a1, 0.f)) << 16);
        }
        hl[p] = d;
    }
    __syncthreads();

    float bb = b2[o];
    float s1 = 0.f, s2 = 0.f;
    __hip_bfloat16* ypl = y2p + (((size_t)(o >> 3) * 192 + bs) * NN) * 8 + (o & 7);

    f32x4 acc[8];
#pragma unroll
    for (int c = 0; c < 8; c++) acc[c] = (f32x4){0.f, 0.f, 0.f, 0.f};

#pragma unroll
    for (int kb = 0; kb < 9; kb++) {
        int4 na, nb; U8 nbf;
        if (kb < 8) {                     // prefetch kb+1 (folds at unroll)
            na = gp[(kb + 1) * 128];
            nb = gp[(kb + 1) * 128 + 1];
            nbf.i = W2B4[(kb + 1) * 64 + l];
        }
        Q d[8];
        d[0].v = hl[ia.x]; d[1].v = hl[ia.y]; d[2].v = hl[ia.z]; d[3].v = hl[ia.w];
        d[4].v = hl[ib.x]; d[5].v = hl[ib.y]; d[6].v = hl[ib.z]; d[7].v = hl[ib.w];
#pragma unroll
        for (int c = 0; c < 8; c++) {
            const int q2 = c >> 1;
            const unsigned sel = (c & 1) ? PERM_HI : PERM_LO;
            U8 Af;
            Af.i.x = __builtin_amdgcn_perm(d[1].u[q2], d[0].u[q2], sel);
            Af.i.y = __builtin_amdgcn_perm(d[3].u[q2], d[2].u[q2], sel);
            Af.i.z = __builtin_amdgcn_perm(d[5].u[q2], d[4].u[q2], sel);
            Af.i.w = __builtin_amdgcn_perm(d[7].u[q2], d[6].u[q2], sel);
            acc[c] = __builtin_amdgcn_mfma_f32_16x16x32_bf16(Af.b, bf.b, acc[c], 0, 0, 0);
        }
        if (kb < 8) { ia = na; ib = nb; bf = nbf; }
    }

    // proven epilogue: scattered bf16 stores into y2 octet planes
    int rbase = w * 16 + q * 4;
#pragma unroll
    for (int c = 0; c < 8; c++) {
        int C = pl * 8 + c;               // layer-2 input channel -> n-block
#pragma unroll
        for (int i = 0; i < 4; i++) {
            float v = acc[c][i] + bb;
            s1 += v; s2 += v * v;
            int n = C * 128 + rbase + i;
            ypl[(size_t)n * 8] = __float2bfloat16(v);
        }
    }

    s1 += __shfl_xor(s1, 16); s1 += __shfl_xor(s1, 32);
    s2 += __shfl_xor(s2, 16); s2 += __shfl_xor(s2, 32);
    if (l < 16) { wred[0][w][l] = s1; wred[1][w][l] = s2; }
    __syncthreads();
    if (tid < 16) {
        float a = 0.f, b = 0.f;
#pragma unroll
        for (int ww = 0; ww < 8; ww++) { a += wred[0][ww][tid]; b += wred[1][ww][tid]; }
        int srow = (bs % NS) * 16 + tid;
        int col  = (bs / NS) * 4 + pl;    // 32 cols
        psum[srow * 32 + col] = a;
        psq [srow * 32 + col] = b;
    }
}

// ---------------------------------------------------------------------------
// Kernel 3: fused BN-stat + BN + relu + layer 3 (MFMA) + relu, 512-thr WG
// per (bs, oct) — unchanged proven body.
// ---------------------------------------------------------------------------
__global__ __launch_bounds__(512, 4) void k_l3bn(const uint4* __restrict__ y2p,
                                                 const int4* __restrict__ G3M4,
                                                 const int4* __restrict__ W3B4,
                                                 const float* __restrict__ psum,
                                                 const float* __restrict__ psq,
                                                 const float* __restrict__ gamma,
                                                 const float* __restrict__ beta,
                                                 const float* __restrict__ b3,
                                                 float* __restrict__ out) {
    __shared__ __align__(16) uint4 zl[4096];       // 64 KB
    __shared__ float scl[8], shf[8];
    int blk = blockIdx.x;                 // 384 = 192 bs * 2 oct
    int oct = blk & 1, bs = blk >> 1;
    int s = bs % NS;
    int tid = threadIdx.x;

    if (tid < 256) {   // BN stat reduce: 8 rows x 32 cols, one value/thread
        int jj = tid >> 5, col = tid & 31;
        int row = s * 16 + oct * 8 + jj;
        float sv = psum[row * 32 + col];
        float qv = psq [row * 32 + col];
        for (int off = 16; off; off >>= 1) {
            sv += __shfl_down(sv, off, 32);
            qv += __shfl_down(qv, off, 32);
        }
        if (col == 0) {
            float mean = sv * (1.0f / BN_COUNT);
            float var  = qv * (1.0f / BN_COUNT) - mean * mean;
            float inv  = rsqrtf(var + 1e-5f);
            int o = oct * 8 + jj;
            float scv = gamma[o] * inv;
            scl[jj] = scv;
            shf[jj] = beta[o] - mean * scv;
        }
    }
    __syncthreads();

    float sc[8], sh[8];
#pragma unroll
    for (int jj = 0; jj < 8; jj++) { sc[jj] = scl[jj]; sh[jj] = shf[jj]; }

    int l = tid & 63, w = tid >> 6;       // w = 0..7
    int o = l & 15, q = l >> 4;

    // prefetch tt=0 / kb=0 idx + B-frag before staging
    const int4* gp0 = G3M4 + (size_t)(w * 5) * 128 + l * 2;       // t = w
    int4 ia = gp0[0];
    int4 ib = gp0[1];
    U8 bf; bf.i = W3B4[l];

    const uint4* yb = y2p + ((size_t)oct * 192 + bs) * NN;
    for (int j = tid; j < 4096; j += 512) {
        uint4 u = yb[j];
        unsigned r[4] = {u.x, u.y, u.z, u.w};
        uint4 pk;
        unsigned* pp = (unsigned*)&pk;
#pragma unroll
        for (int dd = 0; dd < 4; dd++) {
            float lo = fmaxf(fmaf(__uint_as_float(r[dd] << 16),         sc[dd*2],   sh[dd*2]),   0.f);
            float hi = fmaxf(fmaf(__uint_as_float(r[dd] & 0xffff0000u), sc[dd*2+1], sh[dd*2+1]), 0.f);
            unsigned ulo = __float_as_uint(lo) + 0x8000u;   // round to bf16
            unsigned uhi = __float_as_uint(hi) + 0x8000u;
            pp[dd] = __builtin_amdgcn_perm(uhi, ulo, PERM_HI);
        }
        zl[j] = pk;
    }
    __syncthreads();

    float b3v = b3[0];

#pragma unroll
    for (int tt = 0; tt < 2; tt++) {
        int t = tt * 8 + w;               // r-tile 0..15
        const int4* gp = G3M4 + (size_t)(t * 5) * 128 + l * 2;
        f32x4 acc[8];
#pragma unroll
        for (int c = 0; c < 8; c++) acc[c] = (f32x4){0.f, 0.f, 0.f, 0.f};
#pragma unroll
        for (int kb = 0; kb < 5; kb++) {
            int4 na, nb; U8 nbf;
            if (kb < 4) {                 // prefetch kb+1 within this tile
                na = gp[(kb + 1) * 128];
                nb = gp[(kb + 1) * 128 + 1];
                nbf.i = W3B4[(kb + 1) * 64 + l];
            } else if (tt == 0) {         // prefetch next tile's kb=0
                const int4* gpn = G3M4 + (size_t)((8 + w) * 5) * 128 + l * 2;
                na = gpn[0];
                nb = gpn[1];
                nbf.i = W3B4[l];
            }
            Q d[8];
            d[0].v = zl[ia.x]; d[1].v = zl[ia.y]; d[2].v = zl[ia.z]; d[3].v = zl[ia.w];
            d[4].v = zl[ib.x]; d[5].v = zl[ib.y]; d[6].v = zl[ib.z]; d[7].v = zl[ib.w];
#pragma unroll
            for (int c = 0; c < 8; c++) {
                const int q2 = c >> 1;
                const unsigned sel = (c & 1) ? PERM_HI : PERM_LO;
                U8 Af;
                Af.i.x = __builtin_amdgcn_perm(d[1].u[q2], d[0].u[q2], sel);
                Af.i.y = __builtin_amdgcn_perm(d[3].u[q2], d[2].u[q2], sel);
                Af.i.z = __builtin_amdgcn_perm(d[5].u[q2], d[4].u[q2], sel);
                Af.i.w = __builtin_amdgcn_perm(d[7].u[q2], d[6].u[q2], sel);
                acc[c] = __builtin_amdgcn_mfma_f32_16x16x32_bf16(Af.b, bf.b, acc[c], 0, 0, 0);
            }
            if (kb < 4 || tt == 0) { ia = na; ib = nb; bf = nbf; }
        }
        if (o == 0) {                     // C col 0 holds the result
            int rbase = t * 16 + q * 4;
            float* ob = out + (size_t)bs * NN + oct * 2048;
#pragma unroll
            for (int c = 0; c < 8; c++)
#pragma unroll
                for (int i = 0; i < 4; i++)
                    ob[c * 256 + rbase + i] = fmaxf(acc[c][i] + b3v, 0.f);
        }
    }
}

// ---------------------------------------------------------------------------
extern "C" void kernel_launch(void* const* d_in, const int* in_sizes, int n_in,
                              void* d_out, int out_size, void* d_ws, size_t ws_size,
                              hipStream_t stream) {
    const float* input = (const float*)d_in[0];
    const int*   neigh = (const int*)d_in[1];
    const float* W1    = (const float*)d_in[2];
    const float* b1    = (const float*)d_in[3];
    const float* W2    = (const float*)d_in[4];
    const float* b2    = (const float*)d_in[5];
    const float* gamma = (const float*)d_in[6];
    const float* beta  = (const float*)d_in[7];
    const float* W3    = (const float*)d_in[8];
    const float* b3    = (const float*)d_in[9];
    float* out = (float*)d_out;

    // Workspace layout (bytes), all 16B-aligned
    char* ws = (char*)d_ws;
    int*            G2M   = (int*)            (ws);             // 147456
    int*            G3M   = (int*)            (ws + 147456);    // 163840
    __hip_bfloat16* W2B   = (__hip_bfloat16*) (ws + 311296);    // 9216
    __hip_bfloat16* W3B   = (__hip_bfloat16*) (ws + 320512);    // 5120
    float*          flatT = (float*)          (ws + 325632);    // 28311552
    __hip_bfloat16* y2    = (__hip_bfloat16*) (ws + 28637184);  // 25165824
    float*          psum  = (float*)          (ws + 53803008);  // 49152
    float*          psq   = (float*)          (ws + 53852160);  // 49152

    k_prep<<<1100, 256, 0, stream>>>(input, flatT, neigh, G2M, G3M,
                                     W2, W3, W2B, W3B);
    k_l12<<<768, 512, 0, stream>>>(flatT, W1, b1, (const int4*)G2M,
                                   (const int4*)W2B, b2, y2, psum, psq);
    k_l3bn<<<384, 512, 0, stream>>>((const uint4*)y2, (const int4*)G3M,
                                    (const int4*)W3B, psum, psq,
                                    gamma, beta, b3, out);
}